// Round 5
// baseline (1555.289 us; speedup 1.0000x reference)
//
#include <hip/hip_runtime.h>

#define T_DIM 4096
#define C_DIM 2048
#define K_DIM 2048

typedef __bf16 bf16x8 __attribute__((ext_vector_type(8)));
typedef float f32x4 __attribute__((ext_vector_type(4)));

__device__ __forceinline__ unsigned short f2bf(float f) {
  union { float f; unsigned int i; } x;
  x.f = f;
  unsigned int r = x.i + 0x7fffu + ((x.i >> 16) & 1u);  // round-to-nearest-even
  return (unsigned short)(r >> 16);
}

// ---------------- W (K x N) fp32 -> Wt (N x K) bf16 ----------------
__global__ __launch_bounds__(256) void transpose_w(const float* __restrict__ W,
                                                   unsigned short* __restrict__ Wt) {
  __shared__ float tile[64][68];  // +4 pad
  const int c0 = blockIdx.x * 64;  // n
  const int r0 = blockIdx.y * 64;  // k
  const int tid = threadIdx.x;
#pragma unroll
  for (int i = 0; i < 4; ++i) {
    int s = tid + i * 256;  // 0..1023 float4 slots (64 rows x 16 slots)
    int r = s >> 4, c4 = (s & 15) * 4;
    *(float4*)&tile[r][c4] = *(const float4*)&W[(size_t)(r0 + r) * C_DIM + c0 + c4];
  }
  __syncthreads();
#pragma unroll
  for (int i = 0; i < 2; ++i) {
    int s = tid + i * 256;  // 0..511: 64 n-rows x 8 slots of 8 bf16
    int n = s >> 3, k8 = (s & 7) * 8;
    __align__(16) unsigned short tmp[8];
#pragma unroll
    for (int j = 0; j < 8; ++j) tmp[j] = f2bf(tile[k8 + j][n]);
    *(uint4*)&Wt[(size_t)(c0 + n) * K_DIM + r0 + k8] = *(uint4*)tmp;
  }
}

// ------- fused GEMM + rope + relu + bias + tanh + GroupNorm + transpose -------
__global__ __launch_bounds__(256) void gemm_fused(const float* __restrict__ X,
                                                  const unsigned short* __restrict__ Wt,
                                                  const float* __restrict__ hhb,
                                                  const float* __restrict__ gnw,
                                                  const float* __restrict__ gnb,
                                                  float* __restrict__ out) {
  __shared__ __align__(16) unsigned short lsA[128 * 32];  // [m][k] bf16, 8KB
  __shared__ __align__(16) unsigned short lsB[128 * 32];  // [n][k] bf16, 8KB
  __shared__ __align__(16) float lsO[128][68];            // [c][t] fp32, 34.8KB

  const int tid = threadIdx.x;
  const int wave = tid >> 6;
  const int lane = tid & 63;
  const int quad = lane >> 4;
  const int l16 = lane & 15;
  const int wm = wave >> 1, wn = wave & 1;
  const int m0 = blockIdx.y * 128, n0 = blockIdx.x * 128;

  f32x4 acc[4][4];
#pragma unroll
  for (int a = 0; a < 4; ++a)
#pragma unroll
    for (int b = 0; b < 4; ++b)
#pragma unroll
      for (int i = 0; i < 4; ++i) acc[a][b][i] = 0.f;

  // A: 128 rows x 32 k fp32 = 1024 float4 slots; each thread 4.
  // B: 128 rows x 32 k bf16 = 512 uint4 slots; each thread 2.
  for (int k0 = 0; k0 < K_DIM; k0 += 32) {
    float4 av[4];
    uint4 bv[2];
#pragma unroll
    for (int i = 0; i < 4; ++i) {
      int s = tid + i * 256;
      int r = s >> 3, c4 = (s & 7) * 4;
      av[i] = *(const float4*)&X[(size_t)(m0 + r) * K_DIM + k0 + c4];
    }
#pragma unroll
    for (int i = 0; i < 2; ++i) {
      int s = tid + i * 256;
      int r = s >> 2, c8 = (s & 3) * 8;
      bv[i] = *(const uint4*)&Wt[(size_t)(n0 + r) * K_DIM + k0 + c8];
    }
    __syncthreads();  // previous iteration's ds_reads done before overwrite
#pragma unroll
    for (int i = 0; i < 4; ++i) {
      int s = tid + i * 256;
      int r = s >> 3, c4 = (s & 7) * 4;
      unsigned int p0 = (unsigned int)f2bf(av[i].x) | ((unsigned int)f2bf(av[i].y) << 16);
      unsigned int p1 = (unsigned int)f2bf(av[i].z) | ((unsigned int)f2bf(av[i].w) << 16);
      uint2 p = {p0, p1};
      *(uint2*)(lsA + r * 32 + c4) = p;
    }
#pragma unroll
    for (int i = 0; i < 2; ++i) {
      int s = tid + i * 256;
      int r = s >> 2, c8 = (s & 3) * 8;
      *(uint4*)(lsB + r * 32 + c8) = bv[i];
    }
    __syncthreads();  // tiles ready

    bf16x8 af[4], bfr[4];
#pragma unroll
    for (int mf = 0; mf < 4; ++mf)
      af[mf] = *(const bf16x8*)(const void*)(lsA + (wm * 64 + mf * 16 + l16) * 32 + quad * 8);
#pragma unroll
    for (int nf = 0; nf < 4; ++nf)
      bfr[nf] = *(const bf16x8*)(const void*)(lsB + (wn * 64 + nf * 16 + l16) * 32 + quad * 8);
#pragma unroll
    for (int mf = 0; mf < 4; ++mf)
#pragma unroll
      for (int nf = 0; nf < 4; ++nf)
        acc[mf][nf] = __builtin_amdgcn_mfma_f32_16x16x32_bf16(af[mf], bfr[nf], acc[mf][nf], 0, 0, 0);
  }

  // ---- epilogue (all fp32); C/D layout: col = l16 (n), row = quad*4 + r (m) ----
  const int c_base = n0 + wn * 64;  // wave's 64 columns == one GroupNorm group
  const int t_base = (m0 & (T_DIM - 1)) + wm * 64;

  float hb[4], gw[4], gb[4];
#pragma unroll
  for (int nf = 0; nf < 4; ++nf) {
    int c = c_base + nf * 16 + l16;
    hb[nf] = hhb[c];
    gw[nf] = gnw[c];
    gb[nf] = gnb[c];
  }

  // rope on channels 0..63 (exactly the c_base==0 wave); pair partner is lane^1
  if (c_base == 0) {
#pragma unroll
    for (int nf = 0; nf < 4; ++nf) {
      int c = nf * 16 + l16;
      int ii = c >> 1;
      float freq = expf(-(float)ii * 0.28782313662425572f);  // 10000^(-ii/32)
      float sgn = (c & 1) ? 1.f : -1.f;
#pragma unroll
      for (int mf = 0; mf < 4; ++mf)
#pragma unroll
        for (int r = 0; r < 4; ++r) {
          float v = acc[mf][nf][r];
          float p = __shfl_xor(v, 1, 64);
          int t = t_base + mf * 16 + quad * 4 + r;
          float ang = (float)t * freq;
          float s = sinf(ang);
          float co = cosf(ang);
          acc[mf][nf][r] = v * co + sgn * p * s;
        }
    }
  }

  // relu -> +bias -> tanh -> GroupNorm (64-ch group == this wave's columns)
#pragma unroll
  for (int mf = 0; mf < 4; ++mf)
#pragma unroll
    for (int r = 0; r < 4; ++r) {
      float h[4];
      float s1 = 0.f, s2 = 0.f;
#pragma unroll
      for (int nf = 0; nf < 4; ++nf) {
        float v = fmaxf(acc[mf][nf][r], 0.f) + hb[nf];
        float th = tanhf(v);
        h[nf] = th;
        s1 += th;
        s2 += th * th;
      }
      // butterfly over l16 bits (quad preserved): sums the 16 lanes x 4 nf = 64 ch
#pragma unroll
      for (int d = 1; d < 16; d <<= 1) {
        s1 += __shfl_xor(s1, d, 64);
        s2 += __shfl_xor(s2, d, 64);
      }
      float mu = s1 * 0.015625f;
      float var = s2 * 0.015625f - mu * mu;
      float rstd = rsqrtf(var + 1e-5f);
#pragma unroll
      for (int nf = 0; nf < 4; ++nf)
        acc[mf][nf][r] = (h[nf] - mu) * rstd * gw[nf] + gb[nf];  // y in place
    }

  // ---- transposed store via LDS, two 64-row chunks (wm==h waves own chunk h) ----
  const int bb = m0 >> 12;          // batch
  const int t0 = m0 & (T_DIM - 1);  // t of block row 0
#pragma unroll
  for (int h = 0; h < 2; ++h) {
    if (wm == h) {
#pragma unroll
      for (int mf = 0; mf < 4; ++mf)
#pragma unroll
        for (int r = 0; r < 4; ++r) {
          int t_in = mf * 16 + quad * 4 + r;
#pragma unroll
          for (int nf = 0; nf < 4; ++nf)
            lsO[wn * 64 + nf * 16 + l16][t_in] = acc[mf][nf][r];
        }
    }
    __syncthreads();
    // 128 c x 64 t floats = 2048 float4 slots; each thread 8
#pragma unroll
    for (int i = 0; i < 8; ++i) {
      int s = tid + i * 256;
      int cl = s >> 4;
      int t4 = (s & 15) * 4;
      float4 v = *(const float4*)&lsO[cl][t4];
      *(float4*)&out[(size_t)bb * C_DIM * T_DIM + (size_t)(n0 + cl) * T_DIM + t0 + h * 64 + t4] = v;
    }
    __syncthreads();  // before next chunk overwrites lsO
  }
}

// ---------------- S_n passthrough: (2,2048) fp32 after the big tensor ----------------
__global__ __launch_bounds__(256) void copy_sn(const float* __restrict__ src,
                                               float* __restrict__ dst) {
  int i = blockIdx.x * 256 + threadIdx.x;  // 0..4095
  dst[i] = src[i];
}

extern "C" void kernel_launch(void* const* d_in, const int* in_sizes, int n_in,
                              void* d_out, int out_size, void* d_ws, size_t ws_size,
                              hipStream_t stream) {
  const float* X = (const float*)d_in[0];
  const float* Sn = (const float*)d_in[1];
  const float* W = (const float*)d_in[2];
  const float* hhb = (const float*)d_in[3];
  const float* gnw = (const float*)d_in[4];
  const float* gnb = (const float*)d_in[5];
  float* out = (float*)d_out;
  unsigned short* Wt = (unsigned short*)d_ws;  // 8 MB bf16 scratch

  transpose_w<<<dim3(32, 32), dim3(256), 0, stream>>>(W, Wt);
  gemm_fused<<<dim3(16, 64), dim3(256), 0, stream>>>(X, Wt, hhb, gnw, gnb, out);
  copy_sn<<<dim3(16), dim3(256), 0, stream>>>(Sn, out + (size_t)16777216);
}